// Round 8
// baseline (170.567 us; speedup 1.0000x reference)
//
#include <hip/hip_runtime.h>

#define NQ   10000
#define BSZ  2
#define DIM  256
#define NH   8
#define HD   32
#define NLV  4
#define NPT  4
#define NV   13294           // 10000 + 2500 + 625 + 169
#define MT   (BSZ*NQ)        // 20000 rows
#define NOUT 384             // 256 offsets + 128 attn logits
#define NVAL (BSZ*NV*NH*HD)  // 6,806,528 f32 elements in value
#define GEMM_BLOCKS 939      // 3 x 313
#define PREP_BLOCKS 6647     // NVAL/4/256

typedef float    floatx4 __attribute__((ext_vector_type(4)));
typedef int      intx4   __attribute__((ext_vector_type(4)));
typedef __bf16   bf16x8  __attribute__((ext_vector_type(8)));
typedef _Float16 halfx8  __attribute__((ext_vector_type(8)));
typedef _Float16 halfx4  __attribute__((ext_vector_type(4)));

__device__ __forceinline__ unsigned short f32_to_bf16(float f) {
  unsigned int u = __float_as_uint(f);
  u += 0x7FFFu + ((u >> 16) & 1u);   // RNE
  return (unsigned short)(u >> 16);
}

// ---------------- merged prep + GEMM (independent work, overlapped on CUs) ----------
// bid < GEMM_BLOCKS: 64x128 MFMA tile of raw = Q @ [W_off;W_attn]^T + bias
// else:              value f32 -> f16 cast (one float4 per thread)
//                    (f16 not bf16: enables v_fma_mix_f32 in sample phase 4)
__global__ __launch_bounds__(256) void gp_kernel(
    const float* __restrict__ query, const float* __restrict__ W_off,
    const float* __restrict__ W_attn,
    const float* __restrict__ b_off, const float* __restrict__ b_attn,
    const float* __restrict__ value,
    float* __restrict__ raw, _Float16* __restrict__ vf16) {
  const int bid = blockIdx.x;
  const int tid = threadIdx.x;
  if (bid >= GEMM_BLOCKS) {          // ---- prep part ----
    int i = (bid - GEMM_BLOCKS) * 256 + tid;
    if (i * 4 < NVAL) {
      floatx4 v = *(const floatx4*)&value[i * 4];
      halfx4 t = { (_Float16)v.x, (_Float16)v.y, (_Float16)v.z, (_Float16)v.w };
      *(uint2*)&vf16[i * 4] = *(const uint2*)&t;
    }
    return;
  }
  // ---- gemm part ----
  __shared__ unsigned short As[64][40];    // +8 pad
  __shared__ unsigned short Bs[128][40];
  const int n0 = (bid % 3) * 128;
  const int m0 = (bid / 3) * 64;
  const int wave = tid >> 6;
  const int lane = tid & 63;
  const int quad = lane >> 4;
  const int l16  = lane & 15;
  floatx4 acc[8] = {};
  const int ar = tid >> 2;        // 0..63
  const int ac = (tid & 3) * 8;   // 0,8,16,24
  const int br = tid >> 1;        // 0..127
  const int bc = (tid & 1) * 16;  // 0,16
  const float* __restrict__ Wsrc =
      (n0 < 256) ? (W_off + (size_t)n0 * DIM) : (W_attn + (size_t)(n0 - 256) * DIM);

  for (int k0 = 0; k0 < DIM; k0 += 32) {
    {
      int gm = m0 + ar;
      floatx4 a0 = {}, a1 = {};
      if (gm < MT) {
        const float* src = query + (size_t)gm * DIM + k0 + ac;
        a0 = *(const floatx4*)src;
        a1 = *(const floatx4*)(src + 4);
      }
      unsigned short t[8];
      t[0]=f32_to_bf16(a0.x); t[1]=f32_to_bf16(a0.y); t[2]=f32_to_bf16(a0.z); t[3]=f32_to_bf16(a0.w);
      t[4]=f32_to_bf16(a1.x); t[5]=f32_to_bf16(a1.y); t[6]=f32_to_bf16(a1.z); t[7]=f32_to_bf16(a1.w);
      *(uint4*)&As[ar][ac] = *(const uint4*)t;
    }
    {
      const float* src = Wsrc + (size_t)br * DIM + k0 + bc;
      floatx4 b0 = *(const floatx4*)src;
      floatx4 b1 = *(const floatx4*)(src + 4);
      floatx4 b2 = *(const floatx4*)(src + 8);
      floatx4 b3 = *(const floatx4*)(src + 12);
      unsigned short t[16];
      t[0]=f32_to_bf16(b0.x);  t[1]=f32_to_bf16(b0.y);  t[2]=f32_to_bf16(b0.z);  t[3]=f32_to_bf16(b0.w);
      t[4]=f32_to_bf16(b1.x);  t[5]=f32_to_bf16(b1.y);  t[6]=f32_to_bf16(b1.z);  t[7]=f32_to_bf16(b1.w);
      t[8]=f32_to_bf16(b2.x);  t[9]=f32_to_bf16(b2.y);  t[10]=f32_to_bf16(b2.z); t[11]=f32_to_bf16(b2.w);
      t[12]=f32_to_bf16(b3.x); t[13]=f32_to_bf16(b3.y); t[14]=f32_to_bf16(b3.z); t[15]=f32_to_bf16(b3.w);
      *(uint4*)&Bs[br][bc]     = *(const uint4*)t;
      *(uint4*)&Bs[br][bc + 8] = *(const uint4*)(t + 8);
    }
    __syncthreads();
    bf16x8 a = *(const bf16x8*)&As[wave*16 + l16][quad*8];
    #pragma unroll
    for (int nt = 0; nt < 8; nt++) {
      bf16x8 b = *(const bf16x8*)&Bs[nt*16 + l16][quad*8];
      acc[nt] = __builtin_amdgcn_mfma_f32_16x16x32_bf16(a, b, acc[nt], 0, 0, 0);
    }
    __syncthreads();
  }
  #pragma unroll
  for (int nt = 0; nt < 8; nt++) {
    int gn = n0 + nt*16 + l16;
    float bias = (gn < 256) ? b_off[gn] : b_attn[gn - 256];
    #pragma unroll
    for (int r = 0; r < 4; r++) {
      int gm = m0 + wave*16 + quad*4 + r;
      if (gm < MT) raw[(size_t)gm*NOUT + gn] = acc[nt][r] + bias;
    }
  }
}

// ---------------- softmax + bilinear sampling (f16 value, v_fma_mix MACs) ----------
// Block = 256 threads = 4 waves, EIGHT queries (2 per wave). LDS 30,464 B.
//  1) 1024 slots (ql,h,l,p): logits -> s_aw (17-stride); px,py in REGISTERS
//  2) softmax per (ql,h): 64 rows, one full wave
//  3) s_off[(ql*8+h)*68 + lp*4] = 4 tap byte-offsets (idx*512+h*64; OOB->0)
//     s_w [(ql*8+h)*34 + lp*2] = 4 aw-folded weights as packed f16 pairs
//  4) wave = 2 queries; lane=(qh,h,cq): 16 pts x (ds_read_b128 + ds_read_b64 +
//     4 global_load_dwordx4 (8 f16 ch) + 32 v_fma_mix_f32); 2x float4 store
__global__ __launch_bounds__(256) void sample_kernel(
    const float* __restrict__ raw, const _Float16* __restrict__ vf16,
    const float* __restrict__ refp, float* __restrict__ tmp) {
  const int b  = blockIdx.y;
  const int q0 = blockIdx.x * 8;
  const int mbase = b * NQ + q0;
  const int tid = threadIdx.x;

  __shared__ int          s_off[64 * 68];   // 17,408 B
  __shared__ unsigned int s_w  [64 * 34];   //  8,704 B
  __shared__ float        s_aw [64 * 17];   //  4,352 B

  const int WLI[4] = {100, 50, 25, 13};
  const int STI[4] = {0, 10000, 12500, 13125};

  float rpx[4], rpy[4];

  // ---- phase 1: coords (registers) + logits (LDS) ----
  #pragma unroll
  for (int it = 0; it < 4; ++it) {
    int slot = it * 256 + tid;
    int ql = slot >> 7, r = slot & 127, h = r >> 4, lp = r & 15, l = lp >> 2, p = lp & 3;
    int m = mbase + ql;
    const float* rp = raw + (size_t)m * NOUT;
    float offx = rp[h*32 + l*8 + p*2 + 0];
    float offy = rp[h*32 + l*8 + p*2 + 1];
    s_aw[(ql*8 + h)*17 + lp] = rp[256 + h*16 + lp];
    float Wl = (float)WLI[l];
    float rx = refp[(m*NLV + l)*2 + 0];
    float ry = refp[(m*NLV + l)*2 + 1];
    // (ref + off/W)*2-1 -> pixel (align_corners=False): ref*W + off - 0.5
    rpx[it] = rx * Wl + offx - 0.5f;
    rpy[it] = ry * Wl + offy - 0.5f;
  }
  __syncthreads();

  // ---- phase 2: softmax over 16 logits per (ql,h), in place; one full wave ----
  if (tid < 64) {
    int base = tid * 17;
    float mx = -1e30f;
    #pragma unroll
    for (int i = 0; i < 16; i++) mx = fmaxf(mx, s_aw[base + i]);
    float s = 0.f;
    float e[16];
    #pragma unroll
    for (int i = 0; i < 16; i++) { e[i] = expf(s_aw[base + i] - mx); s += e[i]; }
    float inv = 1.f / s;
    #pragma unroll
    for (int i = 0; i < 16; i++) s_aw[base + i] = e[i] * inv;
  }
  __syncthreads();

  // ---- phase 3: tap offsets + packed f16 weights ----
  #pragma unroll
  for (int it = 0; it < 4; ++it) {
    int slot = it * 256 + tid;
    int ql = slot >> 7, r = slot & 127, h = r >> 4, lp = r & 15, l = lp >> 2;
    int rowqh = ql*8 + h;
    float aw = s_aw[rowqh*17 + lp];
    float px = rpx[it], py = rpy[it];
    float x0f = floorf(px), y0f = floorf(py);
    int x0 = (int)x0f, y0 = (int)y0f;
    float wx1 = px - x0f, wx0 = 1.f - wx1;
    float wy1 = py - y0f, wy0 = 1.f - wy1;
    int Wl = WLI[l], STl = STI[l];
    int offs[4]; halfx4 wb;
    #pragma unroll
    for (int t = 0; t < 4; ++t) {
      int xi = x0 + (t & 1), yi = y0 + (t >> 1);
      bool inb = (xi >= 0) & (xi < Wl) & (yi >= 0) & (yi < Wl);
      offs[t] = inb ? ((STl + yi*Wl + xi) * 512 + h * 64) : 0;  // f16 bytes
      float w = inb ? (aw * ((t & 1) ? wx1 : wx0) * ((t >> 1) ? wy1 : wy0)) : 0.f;
      wb[t] = (_Float16)w;
    }
    *(intx4*)&s_off[rowqh*68 + lp*4] = *(const intx4*)offs;
    *(uint2*)&s_w[rowqh*34 + lp*2] = *(const uint2*)&wb;
  }
  __syncthreads();

  // ---- phase 4: accumulate; wave = 2 queries, lane = (qh, h, cq) ----
  const int wv = tid >> 6, lane = tid & 63;
  const int qh = lane >> 5, ql = wv*2 + qh;
  const int h = (lane >> 2) & 7, cq = lane & 3;
  const char* vb = (const char*)vf16 + (size_t)b * (NV*NH*HD*2) + cq * 16;
  floatx4 acc0 = {0.f,0.f,0.f,0.f}, acc1 = {0.f,0.f,0.f,0.f};
  const int orow = (ql*8 + h) * 68, wrow = (ql*8 + h) * 34;
  #pragma unroll 4
  for (int pt = 0; pt < 16; ++pt) {
    intx4 offs = *(const intx4*)&s_off[orow + pt*4];
    uint2 wp   = *(const uint2*)&s_w[wrow + pt*2];
    halfx4 hw  = *(const halfx4*)&wp;
    halfx8 v0 = *(const halfx8*)(vb + offs.x);
    halfx8 v1 = *(const halfx8*)(vb + offs.y);
    halfx8 v2 = *(const halfx8*)(vb + offs.z);
    halfx8 v3 = *(const halfx8*)(vb + offs.w);
    #pragma unroll
    for (int t = 0; t < 4; ++t) {
      halfx8 v = (t==0) ? v0 : (t==1) ? v1 : (t==2) ? v2 : v3;
      float w = (float)hw[t];
      // fma(fpext(f16), f32, f32) -> v_fma_mix_f32 (1 instr per channel-MAC)
      acc0.x += w * (float)v[0];
      acc0.y += w * (float)v[1];
      acc0.z += w * (float)v[2];
      acc0.w += w * (float)v[3];
      acc1.x += w * (float)v[4];
      acc1.y += w * (float)v[5];
      acc1.z += w * (float)v[6];
      acc1.w += w * (float)v[7];
    }
  }
  int m = mbase + ql;
  float* dst = &tmp[(size_t)m * DIM + h*HD + cq*8];
  *(floatx4*)dst       = acc0;
  *(floatx4*)(dst + 4) = acc1;
}

// ---------------- transpose tmp[b,q,ch] -> out[b,ch,q] ----------------
__global__ __launch_bounds__(256) void transpose_kernel(
    const float* __restrict__ tmp, float* __restrict__ out) {
  __shared__ float tile[32][33];
  const int b  = blockIdx.z;
  const int q0 = blockIdx.x * 32;
  const int c0 = blockIdx.y * 32;
  const int tx = threadIdx.x & 31;
  const int ty = threadIdx.x >> 5;   // 0..7
  #pragma unroll
  for (int i = 0; i < 4; i++) {
    int qq = q0 + ty + i*8;
    tile[ty + i*8][tx] = (qq < NQ) ? tmp[((long)b*NQ + qq)*DIM + c0 + tx] : 0.f;
  }
  __syncthreads();
  if (q0 + tx < NQ) {
    #pragma unroll
    for (int i = 0; i < 4; i++) {
      out[((long)b*DIM + c0 + ty + i*8)*NQ + q0 + tx] = tile[tx][ty + i*8];
    }
  }
}

extern "C" void kernel_launch(void* const* d_in, const int* in_sizes, int n_in,
                              void* d_out, int out_size, void* d_ws, size_t ws_size,
                              hipStream_t stream) {
  const float* query  = (const float*)d_in[0];
  const float* value  = (const float*)d_in[1];
  const float* refp   = (const float*)d_in[2];
  // d_in[3] = spatial_shapes (constants hardcoded)
  const float* W_off  = (const float*)d_in[4];
  const float* b_off  = (const float*)d_in[5];
  const float* W_attn = (const float*)d_in[6];
  const float* b_attn = (const float*)d_in[7];
  float* out = (float*)d_out;

  char* ws = (char*)d_ws;
  float*     raw  = (float*)ws;                      // 30,720,000 B
  float*     tmp  = (float*)(ws + 30720000);         // 20,480,000 B
  _Float16*  vf16 = (_Float16*)(ws + 51200000);      // 13,613,056 B

  hipLaunchKernelGGL(gp_kernel, dim3(GEMM_BLOCKS + PREP_BLOCKS), dim3(256), 0, stream,
                     query, W_off, W_attn, b_off, b_attn, value, raw, vf16);
  hipLaunchKernelGGL(sample_kernel, dim3(NQ / 8, BSZ), dim3(256), 0, stream,
                     raw, vf16, refp, tmp);
  hipLaunchKernelGGL(transpose_kernel, dim3(313, 8, 2), dim3(256), 0, stream,
                     tmp, out);
}